// Round 9
// baseline (94.767 us; speedup 1.0000x reference)
//
#include <hip/hip_runtime.h>
#include <hip/hip_bf16.h>
#include <string.h>

typedef __attribute__((ext_vector_type(8))) short short8;
typedef __attribute__((ext_vector_type(4))) float f32x4;
typedef __attribute__((ext_vector_type(4))) float float4v;
typedef __attribute__((ext_vector_type(4))) unsigned short ushort4v;

#define LOG2E 1.44269504088896340736f
#define NB 8
#define NN 2048
#define NF 128

static __device__ inline unsigned short f2bf(float x) {
    __hip_bfloat16 b = __float2bfloat16(x);
    unsigned short u;
    __builtin_memcpy(&u, &b, 2);
    return u;
}
static __device__ inline float bf2f(unsigned short u) {
    union { unsigned u; float f; } v;
    v.u = ((unsigned)u) << 16;
    return v.f;
}
// order-preserving float->uint key for atomicMax
static __device__ inline unsigned fkey(float f) {
    unsigned u = __float_as_uint(f);
    return (u & 0x80000000u) ? ~u : (u | 0x80000000u);
}
static __device__ inline float funkey(unsigned k) {
    unsigned b = (k & 0x80000000u) ? (k & 0x7FFFFFFFu) : ~k;
    return __uint_as_float(b);
}
// per-wave dtype sniff over first 512 uint16 of a float tensor (1=bf16,0=f32)
static __device__ inline int wave_sniff(const unsigned short* __restrict__ raw) {
    int lane = threadIdx.x & 63;
    int cnt = 0;
#pragma unroll
    for (int i = 0; i < 8; ++i) {
        int e = (raw[lane * 8 + i] >> 7) & 0xFF;
        cnt += (e >= 102 && e <= 139) ? 1 : 0;
    }
#pragma unroll
    for (int off = 1; off < 64; off <<= 1) cnt += __shfl_xor(cnt, off);
    return cnt >= 450;
}

// ---------------- k_prep: WT hi/lo split-transpose + a vectors + s2m init ---
__global__ __launch_bounds__(256) void k_prep(const void* __restrict__ Wraw,
                                              const void* __restrict__ araw,
                                              short* __restrict__ WThi,
                                              short* __restrict__ WTlo,
                                              float* __restrict__ a1s,
                                              float* __restrict__ a2s,
                                              unsigned* __restrict__ s2mkey) {
    const int bf16w = wave_sniff((const unsigned short*)Wraw);
    int idx = blockIdx.x * 256 + threadIdx.x;   // 0..16383
    int k = idx >> 7, n = idx & 127;
    float x = bf16w ? bf2f(((const unsigned short*)Wraw)[idx])
                    : ((const float*)Wraw)[idx];
    unsigned short hi = f2bf(x);
    float lo = x - bf2f(hi);
    WThi[n * 128 + k] = (short)hi;
    WTlo[n * 128 + k] = (short)f2bf(lo);
    if (blockIdx.x == 0) {
        int i = threadIdx.x;
        float av = bf16w ? bf2f(((const unsigned short*)araw)[i])
                         : ((const float*)araw)[i];
        if (i < 128) a1s[i] = LOG2E * av;
        else a2s[i - 128] = LOG2E * av;
        if (i < NB) s2mkey[i] = 0u;             // below every real key
    }
}

// ---------------- k_gemm: Wh (hi/lo split MFMA) + s1/s2 + s2max atomics -----
__global__ __launch_bounds__(256, 4) void k_gemm(const void* __restrict__ hraw,
                                                 const short* __restrict__ WThi,
                                                 const short* __restrict__ WTlo,
                                                 const float* __restrict__ a1s,
                                                 const float* __restrict__ a2s,
                                                 float* __restrict__ s1,
                                                 float* __restrict__ s2,
                                                 unsigned* __restrict__ s2mkey,
                                                 short* __restrict__ WhT) {
    const int tid = threadIdx.x;
    const int lane = tid & 63;
    const int w = tid >> 6;
    const int lo = lane & 15, g = lane >> 4;
    const int i0 = (blockIdx.x * 4 + w) * 16;   // global row base over B*N
    const int bf16w = wave_sniff((const unsigned short*)hraw);

    short8 ahi[4], alo[4];
    if (bf16w) {
        const short* h16 = (const short*)hraw;
#pragma unroll
        for (int kc = 0; kc < 4; ++kc) {
            ahi[kc] = *(const short8*)(h16 + (size_t)(i0 + lo) * NF + kc * 32 + g * 8);
            alo[kc] = (short8){0, 0, 0, 0, 0, 0, 0, 0};
        }
    } else {
        const float* hf = (const float*)hraw;
#pragma unroll
        for (int kc = 0; kc < 4; ++kc) {
            const float* p = hf + (size_t)(i0 + lo) * NF + kc * 32 + g * 8;
            float4v x0 = *(const float4v*)(p);
            float4v x1 = *(const float4v*)(p + 4);
            short8 h8, l8;
#pragma unroll
            for (int q = 0; q < 4; ++q) {
                unsigned short u0 = f2bf(x0[q]);
                h8[q] = (short)u0;
                l8[q] = (short)f2bf(x0[q] - bf2f(u0));
                unsigned short u1 = f2bf(x1[q]);
                h8[q + 4] = (short)u1;
                l8[q + 4] = (short)f2bf(x1[q] - bf2f(u1));
            }
            ahi[kc] = h8;
            alo[kc] = l8;
        }
    }

    f32x4 acc[8];
#pragma unroll
    for (int t = 0; t < 8; ++t) acc[t] = (f32x4){0.f, 0.f, 0.f, 0.f};
#pragma unroll
    for (int t = 0; t < 8; ++t) {
#pragma unroll
        for (int kc = 0; kc < 4; ++kc) {
            const size_t boff = (size_t)(lo + 16 * t) * NF + kc * 32 + g * 8;
            short8 bhi = *(const short8*)(WThi + boff);
            short8 blo = *(const short8*)(WTlo + boff);
            acc[t] = __builtin_amdgcn_mfma_f32_16x16x32_bf16(ahi[kc], bhi, acc[t], 0, 0, 0);
            acc[t] = __builtin_amdgcn_mfma_f32_16x16x32_bf16(ahi[kc], blo, acc[t], 0, 0, 0);
            acc[t] = __builtin_amdgcn_mfma_f32_16x16x32_bf16(alo[kc], bhi, acc[t], 0, 0, 0);
        }
    }

    const int b = i0 >> 11;
    const int n0 = i0 & 2047;
    short* wt = WhT + (size_t)b * NF * NN;
#pragma unroll
    for (int t = 0; t < 8; ++t) {
        ushort4v u;
#pragma unroll
        for (int r = 0; r < 4; ++r) u[r] = f2bf(acc[t][r]);
        *(ushort4v*)(wt + (size_t)(lo + 16 * t) * NN + n0 + g * 4) = u;
    }

    float a1f[8], a2f[8];
#pragma unroll
    for (int t = 0; t < 8; ++t) {
        a1f[t] = a1s[lo + 16 * t];
        a2f[t] = a2s[lo + 16 * t];
    }
    float wm = -1e30f;
#pragma unroll
    for (int r = 0; r < 4; ++r) {
        float d1 = 0.f, d2 = 0.f;
#pragma unroll
        for (int t = 0; t < 8; ++t) {
            float wv = acc[t][r];
            d1 += wv * a1f[t];
            d2 += wv * a2f[t];
        }
#pragma unroll
        for (int off = 1; off < 16; off <<= 1) {
            d1 += __shfl_xor(d1, off);
            d2 += __shfl_xor(d2, off);
        }
        if (lo == 0) {
            s1[i0 + g * 4 + r] = d1;
            s2[i0 + g * 4 + r] = d2;
        }
        wm = fmaxf(wm, d2);
    }
    wm = fmaxf(wm, __shfl_xor(wm, 16));
    wm = fmaxf(wm, __shfl_xor(wm, 32));
    if (lane == 0) atomicMax(&s2mkey[b], fkey(wm));
}

// ---------------- k_attn5: direct-adj masks + LDS-staged softmax+PV ---------
// block = 256 thr = 4 waves = 4 row-groups (64 rows), j-range NN/JS.
// Prologue: each wave streams its 16 rows' adj coalesced (lane=j, contiguous
// per row) -> __ballot -> LDS mask slab. Then depth-2 V pipeline (R8-proven).
template <int FINAL, int JS>
__global__ __launch_bounds__(256, 4) void k_attn5(const int* __restrict__ adj,
                                                  const float* __restrict__ s1,
                                                  const float* __restrict__ s2,
                                                  const unsigned* __restrict__ s2mkey,
                                                  const short* __restrict__ WhT,
                                                  const void* __restrict__ hraw,
                                                  void* __restrict__ out,
                                                  float* __restrict__ pO,
                                                  float* __restrict__ pL) {
    constexpr int JL = NN / JS;
    constexpr int NT = JL / 64;
    constexpr int PKSTR = NT + 1;   // padded stride -> conflict-free b64 reads

    const int tid = threadIdx.x;
    const int lane = tid & 63, wid = tid >> 6;
    const int lo = lane & 15, g = lane >> 4;
    const int gid = blockIdx.x;
    const int js = (JS > 1) ? (gid / (NB * 32)) : 0;   // js-major grid
    const int rem = gid % (NB * 32);
    const int blk = rem & 31;
    const int b = rem >> 5;
    const int rowbase = blk * 64 + wid * 16;
    const int row = rowbase + lo;
    const int jbeg = js * JL;

    __shared__ short ldsV[2][8192];                 // 2 x [128 f][64 j]
    __shared__ unsigned long long ldsPk[64][PKSTR]; // block's 64 rows
    __shared__ float ldsZ[JL];

    const float s1v = s1[b * NN + row];
    const float s2mv = funkey(s2mkey[b]);
    const float tm = s1v + s2mv;
    const float M = fmaxf(tm, 0.2f * tm);

    // ---- prologue: build adj masks (coalesced row streams + ballot) ----
    {
        const int* abase = adj + (size_t)(b * NN + rowbase) * NN + jbeg + lane;
#pragma unroll 2
        for (int r = 0; r < 16; ++r) {
            const int* ap = abase + (size_t)r * NN;
            int vals[NT];
#pragma unroll
            for (int w = 0; w < NT; ++w) vals[w] = ap[w * 64];
#pragma unroll
            for (int w = 0; w < NT; ++w) {
                unsigned long long m = __ballot(vals[w] > 0);
                if (lane == w) ldsPk[wid * 16 + r][w] = m;
            }
        }
    }
    // ---- s2 slab ----
    for (int i = tid * 4; i < JL; i += 1024)
        *(float4v*)&ldsZ[i] = *(const float4v*)(s2 + b * NN + jbeg + i);

    const int sf = tid >> 1;
    const int sh = tid & 1;
    const short* sbase = WhT + (size_t)b * NF * NN + (size_t)sf * NN + jbeg + sh * 32;
    const unsigned swz = (unsigned)((sf & 7) << 4);
    const unsigned wb0 = (unsigned)(sf * 128 + sh * 64);
    const unsigned rsw = (unsigned)((lo & 7) << 4);

    f32x4 acc[8];
#pragma unroll
    for (int t = 0; t < 8; ++t) acc[t] = (f32x4){0.f, 0.f, 0.f, 0.f};
    float lsum = 0.f;

#define LOADV(R0, R1, R2, R3, t)                                   \
    {                                                              \
        const short* sp_ = sbase + (t) * 64;                       \
        R0 = *(const short8*)(sp_);                                \
        R1 = *(const short8*)(sp_ + 8);                            \
        R2 = *(const short8*)(sp_ + 16);                           \
        R3 = *(const short8*)(sp_ + 24);                           \
    }
#define WRITEV(R0, R1, R2, R3, BUF)                                \
    {                                                              \
        char* wp_ = (char*)(BUF);                                  \
        *(short8*)(wp_ + ((wb0 + 0) ^ swz)) = R0;                  \
        *(short8*)(wp_ + ((wb0 + 16) ^ swz)) = R1;                 \
        *(short8*)(wp_ + ((wb0 + 32) ^ swz)) = R2;                 \
        *(short8*)(wp_ + ((wb0 + 48) ^ swz)) = R3;                 \
    }
#define COMPUTE(t, BUF)                                                        \
    {                                                                          \
        const unsigned long long mcur_ = ldsPk[wid * 16 + lo][t];              \
        const float* zb_ = &ldsZ[(t) * 64 + g * 8];                            \
        float4v z0_ = *(const float4v*)(zb_);                                  \
        float4v z1_ = *(const float4v*)(zb_ + 4);                              \
        float4v z2_ = *(const float4v*)(zb_ + 32);                             \
        float4v z3_ = *(const float4v*)(zb_ + 36);                             \
        const unsigned bits0_ = (unsigned)(mcur_ >> (g * 8)) & 0xFFu;          \
        const unsigned bits1_ = (unsigned)(mcur_ >> (32 + g * 8)) & 0xFFu;     \
        short8 pa0_, pa1_;                                                     \
        _Pragma("unroll") for (int q = 0; q < 4; ++q) {                        \
            float t0 = s1v + z0_[q];                                           \
            float e0 = fmaxf(t0, 0.2f * t0);                                   \
            float p0 = ((bits0_ >> q) & 1u) ? exp2f(e0 - M) : 0.f;             \
            float t1 = s1v + z1_[q];                                           \
            float e1 = fmaxf(t1, 0.2f * t1);                                   \
            float p1 = ((bits0_ >> (q + 4)) & 1u) ? exp2f(e1 - M) : 0.f;       \
            float t2 = s1v + z2_[q];                                           \
            float e2 = fmaxf(t2, 0.2f * t2);                                   \
            float p2 = ((bits1_ >> q) & 1u) ? exp2f(e2 - M) : 0.f;             \
            float t3 = s1v + z3_[q];                                           \
            float e3 = fmaxf(t3, 0.2f * t3);                                   \
            float p3 = ((bits1_ >> (q + 4)) & 1u) ? exp2f(e3 - M) : 0.f;       \
            pa0_[q] = (short)f2bf(p0);                                         \
            pa0_[q + 4] = (short)f2bf(p1);                                     \
            pa1_[q] = (short)f2bf(p2);                                         \
            pa1_[q + 4] = (short)f2bf(p3);                                     \
            lsum += p0 + p1 + p2 + p3;                                         \
        }                                                                      \
        const char* cb_ = (const char*)(BUF);                                  \
        _Pragma("unroll") for (int t8 = 0; t8 < 8; ++t8) {                     \
            const unsigned rb0_ = ((unsigned)((lo + 16 * t8) * 128 + g * 16)) ^ rsw;  \
            const unsigned rb1_ = ((unsigned)((lo + 16 * t8) * 128 + 64 + g * 16)) ^ rsw; \
            short8 v0_ = *(const short8*)(cb_ + rb0_);                         \
            short8 v1_ = *(const short8*)(cb_ + rb1_);                         \
            acc[t8] = __builtin_amdgcn_mfma_f32_16x16x32_bf16(pa0_, v0_, acc[t8], 0, 0, 0); \
            acc[t8] = __builtin_amdgcn_mfma_f32_16x16x32_bf16(pa1_, v1_, acc[t8], 0, 0, 0); \
        }                                                                      \
    }

    short8 A0, A1, A2, A3, B0, B1, B2, B3;
    LOADV(A0, A1, A2, A3, 0);
    WRITEV(A0, A1, A2, A3, ldsV[0]);
    LOADV(B0, B1, B2, B3, 1);
    __syncthreads();

    for (int tt = 0; tt < NT; tt += 2) {
        if (tt + 2 < NT) LOADV(A0, A1, A2, A3, tt + 2);
        COMPUTE(tt, ldsV[0]);
        WRITEV(B0, B1, B2, B3, ldsV[1]);
        __syncthreads();
        if (tt + 3 < NT) LOADV(B0, B1, B2, B3, tt + 3);
        COMPUTE(tt + 1, ldsV[1]);
        if (tt + 2 < NT) WRITEV(A0, A1, A2, A3, ldsV[0]);
        __syncthreads();
    }
#undef LOADV
#undef WRITEV
#undef COMPUTE

    lsum += __shfl_xor(lsum, 16);
    lsum += __shfl_xor(lsum, 32);

    if (FINAL) {
        const int bf16w = wave_sniff((const unsigned short*)hraw);
        float inv[4];
#pragma unroll
        for (int r = 0; r < 4; ++r) inv[r] = 1.0f / __shfl(lsum, g * 4 + r);
#pragma unroll
        for (int t8 = 0; t8 < 8; ++t8) {
#pragma unroll
            for (int r = 0; r < 4; ++r) {
                float x = acc[t8][r] * inv[r];
                float y = (x > 0.f) ? x : (exp2f(x * LOG2E) - 1.0f);
                size_t oi = ((size_t)b * NN + rowbase + g * 4 + r) * NF + lo + 16 * t8;
                if (bf16w) ((__hip_bfloat16*)out)[oi] = __float2bfloat16(y);
                else ((float*)out)[oi] = y;
            }
        }
    } else {
        const int grp = b * 128 + blk * 4 + wid;
        float* po = pO + (size_t)(grp * JS + js) * (16 * NF);
#pragma unroll
        for (int t8 = 0; t8 < 8; ++t8)
#pragma unroll
            for (int r = 0; r < 4; ++r)
                po[(g * 4 + r) * NF + lo + 16 * t8] = acc[t8][r];
        if (g == 0) pL[(grp * JS + js) * 16 + lo] = lsum;
    }
}

// ---------------- k_combine: merge j-split partials, ELU, store (vec4) ------
__global__ __launch_bounds__(256) void k_combine(const float* __restrict__ pO,
                                                 const float* __restrict__ pL,
                                                 const void* __restrict__ hraw,
                                                 void* __restrict__ out,
                                                 int jsplit) {
    const int bf16w = wave_sniff((const unsigned short*)hraw);
    int idx4 = blockIdx.x * 256 + threadIdx.x;
    int base = idx4 * 4;
    if (base >= NB * NN * NF) return;
    int col = base & 127;
    int rowg = base >> 7;
    int r = rowg & 15;
    int grp = rowg >> 4;
    float4v o = (float4v){0.f, 0.f, 0.f, 0.f};
    float l = 0.f;
    for (int js = 0; js < jsplit; ++js) {
        int task = grp * jsplit + js;
        o += *(const float4v*)(pO + (size_t)task * (16 * NF) + r * NF + col);
        l += pL[task * 16 + r];
    }
    float inv = 1.0f / l;
    float y[4];
#pragma unroll
    for (int q = 0; q < 4; ++q) {
        float x = o[q] * inv;
        y[q] = (x > 0.f) ? x : (exp2f(x * LOG2E) - 1.0f);
    }
    if (bf16w) {
        ushort4v u;
#pragma unroll
        for (int q = 0; q < 4; ++q) u[q] = f2bf(y[q]);
        *(ushort4v*)((__hip_bfloat16*)out + base) = u;
    } else {
        *(float4v*)((float*)out + base) = (float4v){y[0], y[1], y[2], y[3]};
    }
}

extern "C" void kernel_launch(void* const* d_in, const int* in_sizes, int n_in,
                              void* d_out, int out_size, void* d_ws, size_t ws_size,
                              hipStream_t stream) {
    const void* h = d_in[0];                    // f32 or bf16 [8][2048][128]
    const int* adj = (const int*)d_in[1];       // int32 [8][2048][2048]
    const void* W = d_in[2];                    // f32 or bf16 [128][128]
    const void* a = d_in[3];                    // f32 or bf16 [256]

    char* ws = (char*)d_ws;
    auto align256 = [](size_t x) { return (x + 255) & ~(size_t)255; };
    size_t off = 0;
    short* WThi = (short*)(ws + off); off = align256(off + (size_t)128 * 128 * 2);
    short* WTlo = (short*)(ws + off); off = align256(off + (size_t)128 * 128 * 2);
    float* a1s = (float*)(ws + off);  off = align256(off + 128 * 4);
    float* a2s = (float*)(ws + off);  off = align256(off + 128 * 4);
    short* WhT = (short*)(ws + off);  off = align256(off + (size_t)NB * NF * NN * 2);
    float* s1 = (float*)(ws + off);   off = align256(off + (size_t)NB * NN * 4);
    float* s2 = (float*)(ws + off);   off = align256(off + (size_t)NB * NN * 4);
    unsigned* s2mkey = (unsigned*)(ws + off); off = align256(off + NB * 4);

    const int ngrp = NB * 128;                   // 16-row groups
    auto need = [&](int js) {
        return off + (size_t)ngrp * js * 16 * NF * 4 + 512 + (size_t)ngrp * js * 16 * 4;
    };
    int jsplit = (ws_size >= need(4)) ? 4 : ((ws_size >= need(2)) ? 2 : 1);
    float* pO = nullptr;
    float* pL = nullptr;
    if (jsplit > 1) {
        size_t pO_bytes = (size_t)ngrp * jsplit * 16 * NF * 4;
        size_t pL_bytes = (size_t)ngrp * jsplit * 16 * 4;
        pO = (float*)(ws + off); off = align256(off + pO_bytes);
        pL = (float*)(ws + off); off = align256(off + pL_bytes);
    }

    k_prep<<<64, 256, 0, stream>>>(W, a, WThi, WTlo, a1s, a2s, s2mkey);
    k_gemm<<<256, 256, 0, stream>>>(h, WThi, WTlo, a1s, a2s, s1, s2, s2mkey, WhT);
    if (jsplit == 4) {
        k_attn5<0, 4><<<NB * 32 * 4, 256, 0, stream>>>(adj, s1, s2, s2mkey, WhT, h,
                                                       d_out, pO, pL);
    } else if (jsplit == 2) {
        k_attn5<0, 2><<<NB * 32 * 2, 256, 0, stream>>>(adj, s1, s2, s2mkey, WhT, h,
                                                       d_out, pO, pL);
    } else {
        k_attn5<1, 1><<<NB * 32, 256, 0, stream>>>(adj, s1, s2, s2mkey, WhT, h,
                                                   d_out, nullptr, nullptr);
    }
    if (jsplit > 1) {
        int nout = NB * NN * NF;
        k_combine<<<(nout / 4 + 255) / 256, 256, 0, stream>>>(pO, pL, h, d_out, jsplit);
    }
}

// Round 10
// 90.432 us; speedup vs baseline: 1.0479x; 1.0479x over previous
//
#include <hip/hip_runtime.h>
#include <hip/hip_bf16.h>
#include <string.h>

typedef __attribute__((ext_vector_type(8))) short short8;
typedef __attribute__((ext_vector_type(4))) float f32x4;
typedef __attribute__((ext_vector_type(4))) float float4v;
typedef __attribute__((ext_vector_type(4))) unsigned short ushort4v;

#define LOG2E 1.44269504088896340736f
#define NB 8
#define NN 2048
#define NF 128
#define PKW (NN / 64)             /* 32 u64 words per row */
#define PKWORDS (NB * NN * PKW)   /* 524288 */

static __device__ inline unsigned short f2bf(float x) {
    __hip_bfloat16 b = __float2bfloat16(x);
    unsigned short u;
    __builtin_memcpy(&u, &b, 2);
    return u;
}
static __device__ inline float bf2f(unsigned short u) {
    union { unsigned u; float f; } v;
    v.u = ((unsigned)u) << 16;
    return v.f;
}
static __device__ inline unsigned fkey(float f) {
    unsigned u = __float_as_uint(f);
    return (u & 0x80000000u) ? ~u : (u | 0x80000000u);
}
static __device__ inline float funkey(unsigned k) {
    unsigned b = (k & 0x80000000u) ? (k & 0x7FFFFFFFu) : ~k;
    return __uint_as_float(b);
}
static __device__ inline int wave_sniff(const unsigned short* __restrict__ raw) {
    int lane = threadIdx.x & 63;
    int cnt = 0;
#pragma unroll
    for (int i = 0; i < 8; ++i) {
        int e = (raw[lane * 8 + i] >> 7) & 0xFF;
        cnt += (e >= 102 && e <= 139) ? 1 : 0;
    }
#pragma unroll
    for (int off = 1; off < 64; off <<= 1) cnt += __shfl_xor(cnt, off);
    return cnt >= 450;
}
// async 16B global->LDS (wave-uniform LDS base + lane*16)
static __device__ inline void glds16(const void* g, void* l) {
    __builtin_amdgcn_global_load_lds(
        (const __attribute__((address_space(1))) void*)g,
        (__attribute__((address_space(3))) void*)l, 16, 0, 0);
}

// ---------------- k_prep: WT hi/lo split-transpose + a vectors + s2m init ---
__global__ __launch_bounds__(256) void k_prep(const void* __restrict__ Wraw,
                                              const void* __restrict__ araw,
                                              short* __restrict__ WThi,
                                              short* __restrict__ WTlo,
                                              float* __restrict__ a1s,
                                              float* __restrict__ a2s,
                                              unsigned* __restrict__ s2mkey) {
    const int bf16w = wave_sniff((const unsigned short*)Wraw);
    int idx = blockIdx.x * 256 + threadIdx.x;
    int k = idx >> 7, n = idx & 127;
    float x = bf16w ? bf2f(((const unsigned short*)Wraw)[idx])
                    : ((const float*)Wraw)[idx];
    unsigned short hi = f2bf(x);
    float lo = x - bf2f(hi);
    WThi[n * 128 + k] = (short)hi;
    WTlo[n * 128 + k] = (short)f2bf(lo);
    if (blockIdx.x == 0) {
        int i = threadIdx.x;
        float av = bf16w ? bf2f(((const unsigned short*)araw)[i])
                         : ((const float*)araw)[i];
        if (i < 128) a1s[i] = LOG2E * av;
        else a2s[i - 128] = LOG2E * av;
        if (i < NB) s2mkey[i] = 0u;
    }
}

// ---------------- k_pack: bit-pack adj (sequential stream - ONLY fast shape) -
__global__ __launch_bounds__(256) void k_pack(const int* __restrict__ adj,
                                              unsigned long long* __restrict__ pk) {
    const int wid = blockIdx.x * 4 + (threadIdx.x >> 6);
    const int lane = threadIdx.x & 63;
    const int wpw = PKWORDS / 4096;
    const size_t w0 = (size_t)wid * wpw;
    for (int i = 0; i < wpw; i += 4) {
        int v0 = adj[((w0 + i) << 6) | lane];
        int v1 = adj[((w0 + i + 1) << 6) | lane];
        int v2 = adj[((w0 + i + 2) << 6) | lane];
        int v3 = adj[((w0 + i + 3) << 6) | lane];
        unsigned long long m0 = __ballot(v0 > 0);
        unsigned long long m1 = __ballot(v1 > 0);
        unsigned long long m2 = __ballot(v2 > 0);
        unsigned long long m3 = __ballot(v3 > 0);
        if (lane == 0) {
            pk[w0 + i] = m0;
            pk[w0 + i + 1] = m1;
            pk[w0 + i + 2] = m2;
            pk[w0 + i + 3] = m3;
        }
    }
}

// ---------------- k_gemm: Wh (hi/lo split MFMA) + s1/s2 + s2max atomics -----
__global__ __launch_bounds__(256, 4) void k_gemm(const void* __restrict__ hraw,
                                                 const short* __restrict__ WThi,
                                                 const short* __restrict__ WTlo,
                                                 const float* __restrict__ a1s,
                                                 const float* __restrict__ a2s,
                                                 float* __restrict__ s1,
                                                 float* __restrict__ s2,
                                                 unsigned* __restrict__ s2mkey,
                                                 short* __restrict__ WhT) {
    const int tid = threadIdx.x;
    const int lane = tid & 63;
    const int w = tid >> 6;
    const int lo = lane & 15, g = lane >> 4;
    const int i0 = (blockIdx.x * 4 + w) * 16;
    const int bf16w = wave_sniff((const unsigned short*)hraw);

    short8 ahi[4], alo[4];
    if (bf16w) {
        const short* h16 = (const short*)hraw;
#pragma unroll
        for (int kc = 0; kc < 4; ++kc) {
            ahi[kc] = *(const short8*)(h16 + (size_t)(i0 + lo) * NF + kc * 32 + g * 8);
            alo[kc] = (short8){0, 0, 0, 0, 0, 0, 0, 0};
        }
    } else {
        const float* hf = (const float*)hraw;
#pragma unroll
        for (int kc = 0; kc < 4; ++kc) {
            const float* p = hf + (size_t)(i0 + lo) * NF + kc * 32 + g * 8;
            float4v x0 = *(const float4v*)(p);
            float4v x1 = *(const float4v*)(p + 4);
            short8 h8, l8;
#pragma unroll
            for (int q = 0; q < 4; ++q) {
                unsigned short u0 = f2bf(x0[q]);
                h8[q] = (short)u0;
                l8[q] = (short)f2bf(x0[q] - bf2f(u0));
                unsigned short u1 = f2bf(x1[q]);
                h8[q + 4] = (short)u1;
                l8[q + 4] = (short)f2bf(x1[q] - bf2f(u1));
            }
            ahi[kc] = h8;
            alo[kc] = l8;
        }
    }

    f32x4 acc[8];
#pragma unroll
    for (int t = 0; t < 8; ++t) acc[t] = (f32x4){0.f, 0.f, 0.f, 0.f};
#pragma unroll
    for (int t = 0; t < 8; ++t) {
#pragma unroll
        for (int kc = 0; kc < 4; ++kc) {
            const size_t boff = (size_t)(lo + 16 * t) * NF + kc * 32 + g * 8;
            short8 bhi = *(const short8*)(WThi + boff);
            short8 blo = *(const short8*)(WTlo + boff);
            acc[t] = __builtin_amdgcn_mfma_f32_16x16x32_bf16(ahi[kc], bhi, acc[t], 0, 0, 0);
            acc[t] = __builtin_amdgcn_mfma_f32_16x16x32_bf16(ahi[kc], blo, acc[t], 0, 0, 0);
            acc[t] = __builtin_amdgcn_mfma_f32_16x16x32_bf16(alo[kc], bhi, acc[t], 0, 0, 0);
        }
    }

    const int b = i0 >> 11;
    const int n0 = i0 & 2047;
    short* wt = WhT + (size_t)b * NF * NN;
#pragma unroll
    for (int t = 0; t < 8; ++t) {
        ushort4v u;
#pragma unroll
        for (int r = 0; r < 4; ++r) u[r] = f2bf(acc[t][r]);
        *(ushort4v*)(wt + (size_t)(lo + 16 * t) * NN + n0 + g * 4) = u;
    }

    float a1f[8], a2f[8];
#pragma unroll
    for (int t = 0; t < 8; ++t) {
        a1f[t] = a1s[lo + 16 * t];
        a2f[t] = a2s[lo + 16 * t];
    }
    float wm = -1e30f;
#pragma unroll
    for (int r = 0; r < 4; ++r) {
        float d1 = 0.f, d2 = 0.f;
#pragma unroll
        for (int t = 0; t < 8; ++t) {
            float wv = acc[t][r];
            d1 += wv * a1f[t];
            d2 += wv * a2f[t];
        }
#pragma unroll
        for (int off = 1; off < 16; off <<= 1) {
            d1 += __shfl_xor(d1, off);
            d2 += __shfl_xor(d2, off);
        }
        if (lo == 0) {
            s1[i0 + g * 4 + r] = d1;
            s2[i0 + g * 4 + r] = d2;
        }
        wm = fmaxf(wm, d2);
    }
    wm = fmaxf(wm, __shfl_xor(wm, 16));
    wm = fmaxf(wm, __shfl_xor(wm, 32));
    if (lane == 0) atomicMax(&s2mkey[b], fkey(wm));
}

// ---------------- k_attn6: glds-staged softmax+PV, counted-vmcnt pipeline ---
// block = 256 thr = 4 waves = 4 row-groups (64 rows), j-range NN/JS.
// V staged via global_load_lds: linear LDS dest, inverse-swizzled global src,
// swizzled read. pk/z in LDS slabs (loop has NO stray VMEM -> exact vmcnt).
template <int FINAL, int JS>
__global__ __launch_bounds__(256, 4) void k_attn6(const unsigned long long* __restrict__ pk,
                                                  const float* __restrict__ s1,
                                                  const float* __restrict__ s2,
                                                  const unsigned* __restrict__ s2mkey,
                                                  const short* __restrict__ WhT,
                                                  const void* __restrict__ hraw,
                                                  void* __restrict__ out,
                                                  float* __restrict__ pO,
                                                  float* __restrict__ pL) {
    constexpr int JL = NN / JS;
    constexpr int NT = JL / 64;
    constexpr int PKSTR = NT + 1;
    constexpr int GRID = NB * 32 * JS;

    const int tid = threadIdx.x;
    const int lane = tid & 63, wid = tid >> 6;
    const int lo = lane & 15, g = lane >> 4;
    // XCD-aware swizzle (bijective: GRID % 8 == 0)
    const int gid = (blockIdx.x % 8) * (GRID / 8) + blockIdx.x / 8;
    const int js = (JS > 1) ? (gid / (NB * 32)) : 0;
    const int rem = gid % (NB * 32);
    const int blk = rem & 31;
    const int b = rem >> 5;
    const int rowbase = blk * 64 + wid * 16;
    const int row = rowbase + lo;
    const int jbeg = js * JL;

    __shared__ short ldsV[2][8192];                 // 2 x [128 f][64 j] linear
    __shared__ unsigned long long ldsPk[64][PKSTR];
    __shared__ float ldsZ[JL];

    const float s1v = s1[b * NN + row];
    const float s2mv = funkey(s2mkey[b]);
    const float tm = s1v + s2mv;
    const float M = fmaxf(tm, 0.2f * tm);

    // ---- prologue slabs: pk + z (coalesced, once) ----
    const int jw0 = jbeg >> 6;
    for (int idx = tid; idx < 64 * NT; idx += 256) {
        int r = idx / NT;
        int wp = idx - r * NT;
        ldsPk[r][wp] = pk[((size_t)(b * NN + blk * 64 + r)) * PKW + jw0 + wp];
    }
    for (int i = tid * 4; i < JL; i += 1024)
        *(float4v*)&ldsZ[i] = *(const float4v*)(s2 + b * NN + jbeg + i);

    const unsigned rsw = (unsigned)((lo & 7) << 4);
    const char* wbase = (const char*)(WhT + (size_t)b * NF * NN + jbeg);

// stage tile t into BUF: wave wid covers f-rows [wid*32, wid*32+32)
#define STAGE(t, BUF)                                                          \
    {                                                                          \
        _Pragma("unroll") for (int i_ = 0; i_ < 4; ++i_) {                     \
            const int fr_ = wid * 32 + i_ * 8 + (lane >> 3);                   \
            const unsigned ob_ = (unsigned)((lane & 7) * 16);                  \
            const char* gp_ = wbase + ((size_t)fr_ * NN + (t) * 64) * 2 +      \
                              (ob_ ^ (unsigned)((fr_ & 7) << 4));              \
            glds16(gp_, (char*)(BUF) + wid * 4096 + i_ * 1024);                \
        }                                                                      \
    }
#define COMPUTE(t, BUF)                                                        \
    {                                                                          \
        const unsigned long long mcur_ = ldsPk[wid * 16 + lo][t];              \
        const float* zb_ = &ldsZ[(t) * 64 + g * 8];                            \
        float4v z0_ = *(const float4v*)(zb_);                                  \
        float4v z1_ = *(const float4v*)(zb_ + 4);                              \
        float4v z2_ = *(const float4v*)(zb_ + 32);                             \
        float4v z3_ = *(const float4v*)(zb_ + 36);                             \
        const unsigned bits0_ = (unsigned)(mcur_ >> (g * 8)) & 0xFFu;          \
        const unsigned bits1_ = (unsigned)(mcur_ >> (32 + g * 8)) & 0xFFu;     \
        short8 pa0_, pa1_;                                                     \
        _Pragma("unroll") for (int q = 0; q < 4; ++q) {                        \
            float t0 = s1v + z0_[q];                                           \
            float e0 = fmaxf(t0, 0.2f * t0);                                   \
            float p0 = ((bits0_ >> q) & 1u) ? exp2f(e0 - M) : 0.f;             \
            float t1 = s1v + z1_[q];                                           \
            float e1 = fmaxf(t1, 0.2f * t1);                                   \
            float p1 = ((bits0_ >> (q + 4)) & 1u) ? exp2f(e1 - M) : 0.f;       \
            float t2 = s1v + z2_[q];                                           \
            float e2 = fmaxf(t2, 0.2f * t2);                                   \
            float p2 = ((bits1_ >> q) & 1u) ? exp2f(e2 - M) : 0.f;             \
            float t3 = s1v + z3_[q];                                           \
            float e3 = fmaxf(t3, 0.2f * t3);                                   \
            float p3 = ((bits1_ >> (q + 4)) & 1u) ? exp2f(e3 - M) : 0.f;       \
            pa0_[q] = (short)f2bf(p0);                                         \
            pa0_[q + 4] = (short)f2bf(p1);                                     \
            pa1_[q] = (short)f2bf(p2);                                         \
            pa1_[q + 4] = (short)f2bf(p3);                                     \
            lsum += p0 + p1 + p2 + p3;                                         \
        }                                                                      \
        const char* cb_ = (const char*)(BUF);                                  \
        _Pragma("unroll") for (int t8 = 0; t8 < 8; ++t8) {                     \
            const unsigned rb0_ = ((unsigned)((lo + 16 * t8) * 128 + g * 16)) ^ rsw;  \
            const unsigned rb1_ = ((unsigned)((lo + 16 * t8) * 128 + 64 + g * 16)) ^ rsw; \
            short8 v0_ = *(const short8*)(cb_ + rb0_);                         \
            short8 v1_ = *(const short8*)(cb_ + rb1_);                         \
            acc[t8] = __builtin_amdgcn_mfma_f32_16x16x32_bf16(pa0_, v0_, acc[t8], 0, 0, 0); \
            acc[t8] = __builtin_amdgcn_mfma_f32_16x16x32_bf16(pa1_, v1_, acc[t8], 0, 0, 0); \
        }                                                                      \
    }

    f32x4 acc[8];
#pragma unroll
    for (int t = 0; t < 8; ++t) acc[t] = (f32x4){0.f, 0.f, 0.f, 0.f};
    float lsum = 0.f;

    // prologue: issue tiles 0,1; wait tile0 (4 of 8 glds) + slab ds_writes
    STAGE(0, ldsV[0]);
    STAGE(1, ldsV[1]);
    asm volatile("s_waitcnt vmcnt(4) lgkmcnt(0)" ::: "memory");
    __builtin_amdgcn_s_barrier();
    __builtin_amdgcn_sched_barrier(0);

    int bufsel = 0;
    for (int t = 0; t < NT; ++t) {
        if (bufsel == 0) COMPUTE(t, ldsV[0]) else COMPUTE(t, ldsV[1]);
        asm volatile("s_waitcnt lgkmcnt(0)" ::: "memory");
        __builtin_amdgcn_s_barrier();      // all waves done reading buf[bufsel]
        __builtin_amdgcn_sched_barrier(0);
        if (t + 2 < NT) {
            if (bufsel == 0) STAGE(t + 2, ldsV[0]) else STAGE(t + 2, ldsV[1]);
            asm volatile("s_waitcnt vmcnt(4)" ::: "memory");   // tile t+1 done
        } else {
            asm volatile("s_waitcnt vmcnt(0)" ::: "memory");
        }
        __builtin_amdgcn_s_barrier();      // buf[bufsel^1] ready for all
        __builtin_amdgcn_sched_barrier(0);
        bufsel ^= 1;
    }
#undef STAGE
#undef COMPUTE

    lsum += __shfl_xor(lsum, 16);
    lsum += __shfl_xor(lsum, 32);

    if (FINAL) {
        const int bf16w = wave_sniff((const unsigned short*)hraw);
        float inv[4];
#pragma unroll
        for (int r = 0; r < 4; ++r) inv[r] = 1.0f / __shfl(lsum, g * 4 + r);
#pragma unroll
        for (int t8 = 0; t8 < 8; ++t8) {
#pragma unroll
            for (int r = 0; r < 4; ++r) {
                float x = acc[t8][r] * inv[r];
                float y = (x > 0.f) ? x : (exp2f(x * LOG2E) - 1.0f);
                size_t oi = ((size_t)b * NN + rowbase + g * 4 + r) * NF + lo + 16 * t8;
                if (bf16w) ((__hip_bfloat16*)out)[oi] = __float2bfloat16(y);
                else ((float*)out)[oi] = y;
            }
        }
    } else {
        const int grp = b * 128 + blk * 4 + wid;
        float* po = pO + (size_t)(grp * JS + js) * (16 * NF);
#pragma unroll
        for (int t8 = 0; t8 < 8; ++t8)
#pragma unroll
            for (int r = 0; r < 4; ++r)
                po[(g * 4 + r) * NF + lo + 16 * t8] = acc[t8][r];
        if (g == 0) pL[(grp * JS + js) * 16 + lo] = lsum;
    }
}

// ---------------- k_combine: merge j-split partials, ELU, store (vec4) ------
__global__ __launch_bounds__(256) void k_combine(const float* __restrict__ pO,
                                                 const float* __restrict__ pL,
                                                 const void* __restrict__ hraw,
                                                 void* __restrict__ out,
                                                 int jsplit) {
    const int bf16w = wave_sniff((const unsigned short*)hraw);
    int idx4 = blockIdx.x * 256 + threadIdx.x;
    int base = idx4 * 4;
    if (base >= NB * NN * NF) return;
    int col = base & 127;
    int rowg = base >> 7;
    int r = rowg & 15;
    int grp = rowg >> 4;
    float4v o = (float4v){0.f, 0.f, 0.f, 0.f};
    float l = 0.f;
    for (int js = 0; js < jsplit; ++js) {
        int task = grp * jsplit + js;
        o += *(const float4v*)(pO + (size_t)task * (16 * NF) + r * NF + col);
        l += pL[task * 16 + r];
    }
    float inv = 1.0f / l;
    float y[4];
#pragma unroll
    for (int q = 0; q < 4; ++q) {
        float x = o[q] * inv;
        y[q] = (x > 0.f) ? x : (exp2f(x * LOG2E) - 1.0f);
    }
    if (bf16w) {
        ushort4v u;
#pragma unroll
        for (int q = 0; q < 4; ++q) u[q] = f2bf(y[q]);
        *(ushort4v*)((__hip_bfloat16*)out + base) = u;
    } else {
        *(float4v*)((float*)out + base) = (float4v){y[0], y[1], y[2], y[3]};
    }
}

extern "C" void kernel_launch(void* const* d_in, const int* in_sizes, int n_in,
                              void* d_out, int out_size, void* d_ws, size_t ws_size,
                              hipStream_t stream) {
    const void* h = d_in[0];
    const int* adj = (const int*)d_in[1];
    const void* W = d_in[2];
    const void* a = d_in[3];

    char* ws = (char*)d_ws;
    auto align256 = [](size_t x) { return (x + 255) & ~(size_t)255; };
    size_t off = 0;
    short* WThi = (short*)(ws + off); off = align256(off + (size_t)128 * 128 * 2);
    short* WTlo = (short*)(ws + off); off = align256(off + (size_t)128 * 128 * 2);
    float* a1s = (float*)(ws + off);  off = align256(off + 128 * 4);
    float* a2s = (float*)(ws + off);  off = align256(off + 128 * 4);
    short* WhT = (short*)(ws + off);  off = align256(off + (size_t)NB * NF * NN * 2);
    float* s1 = (float*)(ws + off);   off = align256(off + (size_t)NB * NN * 4);
    float* s2 = (float*)(ws + off);   off = align256(off + (size_t)NB * NN * 4);
    unsigned* s2mkey = (unsigned*)(ws + off); off = align256(off + NB * 4);
    unsigned long long* pk = (unsigned long long*)(ws + off);
    off = align256(off + (size_t)PKWORDS * 8);

    const int ngrp = NB * 128;
    auto need = [&](int js) {
        return off + (size_t)ngrp * js * 16 * NF * 4 + 512 + (size_t)ngrp * js * 16 * 4;
    };
    int jsplit = (ws_size >= need(4)) ? 4 : ((ws_size >= need(2)) ? 2 : 1);
    float* pO = nullptr;
    float* pL = nullptr;
    if (jsplit > 1) {
        size_t pO_bytes = (size_t)ngrp * jsplit * 16 * NF * 4;
        size_t pL_bytes = (size_t)ngrp * jsplit * 16 * 4;
        pO = (float*)(ws + off); off = align256(off + pO_bytes);
        pL = (float*)(ws + off); off = align256(off + pL_bytes);
    }

    k_prep<<<64, 256, 0, stream>>>(W, a, WThi, WTlo, a1s, a2s, s2mkey);
    k_gemm<<<256, 256, 0, stream>>>(h, WThi, WTlo, a1s, a2s, s1, s2, s2mkey, WhT);
    k_pack<<<1024, 256, 0, stream>>>(adj, pk);
    if (jsplit == 4) {
        k_attn6<0, 4><<<NB * 32 * 4, 256, 0, stream>>>(pk, s1, s2, s2mkey, WhT, h,
                                                       d_out, pO, pL);
    } else if (jsplit == 2) {
        k_attn6<0, 2><<<NB * 32 * 2, 256, 0, stream>>>(pk, s1, s2, s2mkey, WhT, h,
                                                       d_out, pO, pL);
    } else {
        k_attn6<1, 1><<<NB * 32, 256, 0, stream>>>(pk, s1, s2, s2mkey, WhT, h,
                                                   d_out, nullptr, nullptr);
    }
    if (jsplit > 1) {
        int nout = NB * NN * NF;
        k_combine<<<(nout / 4 + 255) / 256, 256, 0, stream>>>(pO, pL, h, d_out, jsplit);
    }
}